// Round 14
// baseline (235.153 us; speedup 1.0000x reference)
//
#include <hip/hip_runtime.h>
#include <hip/hip_fp16.h>

#define CAP 10240      // per-coarse-bucket capacity (mean 8184, +20σ safe)

// ---------------- fused: bucketA(LDS-sorted) | gemm1 | gstart ----------------
__global__ __launch_bounds__(1024) void k_fused1(const int* __restrict__ ei,
                                                 const float* __restrict__ x,
                                                 const float* __restrict__ W1,
                                                 const int* __restrict__ batch,
                                                 int* __restrict__ gcnt,
                                                 int* __restrict__ bucketed,
                                                 __half* __restrict__ hLo,
                                                 __half* __restrict__ hHi,
                                                 int* __restrict__ gstart,
                                                 int nA, int nG1, int NB,
                                                 int n, int E, int G) {
    __shared__ __align__(16) char smem[40960];
    int tid = threadIdx.x;
    int bid = blockIdx.x;
    if (bid < nA) {
        // ---- bucketA: register-staged edges -> LDS counting sort -> run writes ----
        int* hist = (int*)smem;            // 512 (count -> cursor)
        int* excl = hist + 512;            // 512 (exclusive scan)
        int* gb   = excl + 512;            // 512 (global base per bucket)
        int* ebuf = gb + 512;              // 8192 sorted entries (32 KB)
        const int* src = ei;
        const int* dst = ei + E;
        for (int i = tid; i < 512; i += 1024) hist[i] = 0;
        __syncthreads();
        int e0 = bid * 8192;
        int d[8], sR[8];
#pragma unroll
        for (int k = 0; k < 8; k++) {
            int e = e0 + k * 1024 + tid;
            bool v = e < E;
            d[k]  = v ? dst[e] : -1;
            sR[k] = v ? src[e] : 0;
            if (v) atomicAdd(&hist[d[k] >> 8], 1);
        }
        __syncthreads();
        // exclusive scan of 512 counts (Hillis-Steele)
        if (tid < 512) excl[tid] = hist[tid];
        __syncthreads();
        for (int off = 1; off < 512; off <<= 1) {
            int v2 = 0;
            if (tid < 512) v2 = excl[tid] + ((tid >= off) ? excl[tid - off] : 0);
            __syncthreads();
            if (tid < 512) excl[tid] = v2;
            __syncthreads();
        }
        if (tid < 512) {
            int c = hist[tid];
            int ex = excl[tid] - c;           // exclusive
            excl[tid] = ex;
            gb[tid] = c ? atomicAdd(&gcnt[tid], c) : 0;
            hist[tid] = ex;                   // reuse as LDS cursor
        }
        __syncthreads();
#pragma unroll
        for (int k = 0; k < 8; k++) {
            if (d[k] >= 0) {
                int b = d[k] >> 8;
                int p = atomicAdd(&hist[b], 1);
                ebuf[p] = (sR[k] << 8) | (d[k] & 255);
            }
        }
        __syncthreads();
        // cooperative run copy: 16-lane group per bucket (64B line per step)
        int grp = tid >> 4, l = tid & 15;     // 64 groups
        for (int t = grp; t < 512; t += 64) {
            int lds0 = excl[t];
            int cnt  = hist[t] - lds0;
            int gb0  = gb[t];
            int* dstp = bucketed + (size_t)t * CAP + gb0;
            for (int k = l; k < cnt; k += 16)
                if (gb0 + k < CAP) dstp[k] = ebuf[lds0 + k];
        }
    } else if (bid < nA + nG1) {
        // ---- gemm1: split-half fp16(x @ W1), 128 rows/block, 4 cols/thread ----
        float* Ws = (float*)smem;            // 128*32 fp32 = 16 KB
        const float4* W4 = (const float4*)W1;
        ((float4*)Ws)[tid] = W4[tid];
        __syncthreads();
        int gb2 = bid - nA;
        int row = gb2 * 128 + (tid >> 3);
        int g8 = tid & 7;
        if (row >= n) return;
        const float4* x4 = (const float4*)x;
        const float4* Ws4 = (const float4*)Ws;
        float a0 = 0.f, a1 = 0.f, a2 = 0.f, a3 = 0.f;
#pragma unroll 4
        for (int j = 0; j < 32; j++) {
            float4 xq = x4[(size_t)row * 32 + j];
#pragma unroll
            for (int t = 0; t < 4; t++) {
                float xv = (t == 0) ? xq.x : (t == 1) ? xq.y : (t == 2) ? xq.z : xq.w;
                float4 wv = Ws4[(4 * j + t) * 8 + g8];
                a0 += xv * wv.x; a1 += xv * wv.y; a2 += xv * wv.z; a3 += xv * wv.w;
            }
        }
        __half2 o[2] = { __floats2half2_rn(a0, a1), __floats2half2_rn(a2, a3) };
        __half* dstp = (g8 < 4) ? (hLo + (size_t)row * 16 + g8 * 4)
                                : (hHi + (size_t)row * 16 + (g8 - 4) * 4);
        *(float2*)dstp = *(const float2*)o;
    } else {
        // ---- gstart from sorted batch ----
        int i = (bid - nA - nG1) * 1024 + tid;
        if (i > n) return;
        if (i == 0) {
            for (int g = 0; g <= batch[0]; g++) gstart[g] = 0;
        } else if (i == n) {
            for (int g = batch[n - 1] + 1; g <= G; g++) gstart[g] = n;
        } else {
            int b = batch[i], p = batch[i - 1];
            for (int g = p + 1; g <= b; g++) gstart[g] = i;
        }
    }
}

// ---------------- bucketB: fine sort + deg/dinv/offs + dinv-scale halves ----------------
__global__ __launch_bounds__(512) void k_bucketB(const int* __restrict__ bucketed,
                                                 const int* __restrict__ gcnt,
                                                 int* __restrict__ csr,
                                                 int* __restrict__ offs,
                                                 int* __restrict__ deg,
                                                 float* __restrict__ dinv,
                                                 __half* __restrict__ hLo,
                                                 __half* __restrict__ hHi, int n) {
    __shared__ int hist[256], scan_a[256], scan_b[256];
    __shared__ float sdinv[256];
    int b = blockIdx.x;
    int tid = threadIdx.x;
    int cnt = min(gcnt[b], CAP);
    int base = b * CAP;                       // fixed-stride csr
    const int* ent = bucketed + (size_t)b * CAP;
    if (tid < 256) hist[tid] = 0;
    __syncthreads();
    for (int i = tid; i < cnt; i += 512) atomicAdd(&hist[ent[i] & 255], 1);
    __syncthreads();
    int h = (tid < 256) ? hist[tid] : 0;
    if (tid < 256) scan_a[tid] = h;
    __syncthreads();
    int* cur = scan_a;
    int* nxt = scan_b;
    for (int off = 1; off < 256; off <<= 1) {
        if (tid < 256) nxt[tid] = cur[tid] + ((tid >= off) ? cur[tid - off] : 0);
        __syncthreads();
        int* tmp = cur; cur = nxt; nxt = tmp;
    }
    if (tid < 256) {
        int ex = cur[tid] - h;
        float dv = rsqrtf((float)(h + 1));    // +1 self-loop
        sdinv[tid] = dv;
        int node = b * 256 + tid;
        if (node < n) {
            offs[node] = base + ex;
            deg[node] = h;
            dinv[node] = dv;
        }
        hist[tid] = ex;      // cursor
    }
    __syncthreads();
    for (int i = tid; i < cnt; i += 512) {
        int v = ent[i];
        int p = atomicAdd(&hist[v & 255], 1);
        csr[base + p] = v >> 8;
    }
    // scale this block's 256 rows (both halves) by dinv
    float4* lo = (float4*)hLo;
    float4* hi = (float4*)hHi;
#pragma unroll
    for (int p = 0; p < 2; p++) {
        int idx = p * 512 + tid;              // 1024 units = 256 nodes * 4 chunks
        int nl = idx >> 2, cg = idx & 3;
        int node = b * 256 + nl;
        if (node < n) {
            float dv = sdinv[nl];
            float4* ptr = (cg < 2) ? &lo[(size_t)node * 2 + cg]
                                   : &hi[(size_t)node * 2 + (cg - 2)];
            float4 raw = *ptr;
            __half2* h2 = (__half2*)&raw;
            __half2 o[4];
#pragma unroll
            for (int j = 0; j < 4; j++) {
                float2 f = __half22float2(h2[j]);
                o[j] = __floats2half2_rn(f.x * dv, f.y * dv);
            }
            *ptr = *(const float4*)o;
        }
    }
}

// ---------------- half-gather: raw sums (neighbors + self), 8 lanes/row ----------------
// lane = o*8 + nb*2 + cg: o = row octant, nb = neighbor slot (4), cg = 16B group (2)
__global__ __launch_bounds__(256) void k_gather_h(const __half* __restrict__ hs,
                                                  const int* __restrict__ csr,
                                                  const int* __restrict__ offs,
                                                  const int* __restrict__ deg,
                                                  __half* __restrict__ out, int n) {
    int wave = threadIdx.x >> 6;
    int lane = threadIdx.x & 63;
    int o  = lane >> 3;       // 0..7 row octant
    int l8 = lane & 7;
    int nb = l8 >> 1;         // 0..3 neighbor slot
    int cg = l8 & 1;          // 0..1 chan group (16 B)
    int row = blockIdx.x * 32 + wave * 8 + o;
    if (row >= n) return;
    int base = offs[row];
    int dg = deg[row];
    const float4* hsv = (const float4*)hs;
    const float4 fz = make_float4(0.f, 0.f, 0.f, 0.f);
    const __half2 hz = __floats2half2_rn(0.f, 0.f);
    __half2 ha0[4], ha1[4];
#pragma unroll
    for (int j = 0; j < 4; j++) { ha0[j] = hz; ha1[j] = hz; }

    int e = nb;
    float4 r0 = (e     < dg) ? hsv[(size_t)csr[base + e    ] * 2 + cg] : fz;
    float4 r1 = (e + 4 < dg) ? hsv[(size_t)csr[base + e + 4] * 2 + cg] : fz;
    while (e < dg) {
        float4 p0 = (e +  8 < dg) ? hsv[(size_t)csr[base + e +  8] * 2 + cg] : fz;
        float4 p1 = (e + 12 < dg) ? hsv[(size_t)csr[base + e + 12] * 2 + cg] : fz;
        const __half2* h0 = (const __half2*)&r0;
        const __half2* h1 = (const __half2*)&r1;
#pragma unroll
        for (int j = 0; j < 4; j++) {
            ha0[j] = __hadd2(ha0[j], h0[j]);
            ha1[j] = __hadd2(ha1[j], h1[j]);
        }
        r0 = p0; r1 = p1; e += 8;
    }
    float acc[8];
#pragma unroll
    for (int j = 0; j < 4; j++) {
        float2 f0 = __half22float2(ha0[j]);
        float2 f1 = __half22float2(ha1[j]);
        acc[2 * j]     = f0.x + f1.x;
        acc[2 * j + 1] = f0.y + f1.y;
    }
    // butterfly over nb (lane bits 1..2)
#pragma unroll
    for (int m = 2; m <= 4; m <<= 1)
#pragma unroll
        for (int j = 0; j < 8; j++) acc[j] += __shfl_xor(acc[j], m, 64);
    // + self (pre-scaled), write raw sum
    float4 sraw = hsv[(size_t)row * 2 + cg];
    const __half2* sh2 = (const __half2*)&sraw;
    if (nb == 0) {
        __half2 ov[4];
#pragma unroll
        for (int j = 0; j < 4; j++) {
            float2 f = __half22float2(sh2[j]);
            ov[j] = __floats2half2_rn(acc[2 * j] + f.x, acc[2 * j + 1] + f.y);
        }
        ((float4*)out)[(size_t)row * 2 + cg] = *(const float4*)ov;
    }
}

// ---------------- ln_split: dinv + bias + LN + ReLU + dinv, re-split halves ----------------
__global__ __launch_bounds__(256) void k_ln_split(const __half* __restrict__ aggLo,
                                                  const __half* __restrict__ aggHi,
                                                  const float* __restrict__ dinv,
                                                  const float* __restrict__ b,
                                                  const float* __restrict__ g,
                                                  const float* __restrict__ be,
                                                  __half* __restrict__ outLo,
                                                  __half* __restrict__ outHi, int n) {
    int tid = threadIdx.x;
    int rl = tid >> 2;        // 64 rows/block
    int l4 = tid & 3;         // chan chunk 0..3 (8 ch each)
    int row = blockIdx.x * 64 + rl;
    if (row >= n) return;
    const float4* lo = (const float4*)aggLo;
    const float4* hi = (const float4*)aggHi;
    float4 raw = (l4 < 2) ? lo[(size_t)row * 2 + l4] : hi[(size_t)row * 2 + (l4 - 2)];
    float dv = dinv[row];
    int c0 = l4 * 8;
    const __half2* h2 = (const __half2*)&raw;
    float a[8];
    float s = 0.f;
#pragma unroll
    for (int j = 0; j < 4; j++) {
        float2 f = __half22float2(h2[j]);
        a[2 * j]     = f.x * dv + b[c0 + 2 * j];
        a[2 * j + 1] = f.y * dv + b[c0 + 2 * j + 1];
        s += a[2 * j] + a[2 * j + 1];
    }
#pragma unroll
    for (int m = 1; m <= 2; m <<= 1) s += __shfl_xor(s, m, 64);
    float mu = s * (1.0f / 32.0f);
    float v2 = 0.f;
#pragma unroll
    for (int j = 0; j < 8; j++) { a[j] -= mu; v2 += a[j] * a[j]; }
#pragma unroll
    for (int m = 1; m <= 2; m <<= 1) v2 += __shfl_xor(v2, m, 64);
    float inv = rsqrtf(v2 * (1.0f / 32.0f) + 1e-5f);
    __half2 ov[4];
#pragma unroll
    for (int j = 0; j < 4; j++) {
        float y0 = fmaxf(a[2 * j]     * inv * g[c0 + 2 * j]     + be[c0 + 2 * j],     0.f) * dv;
        float y1 = fmaxf(a[2 * j + 1] * inv * g[c0 + 2 * j + 1] + be[c0 + 2 * j + 1], 0.f) * dv;
        ov[j] = __floats2half2_rn(y0, y1);
    }
    float4* dstp = (l4 < 2) ? ((float4*)outLo + (size_t)row * 2 + l4)
                            : ((float4*)outHi + (size_t)row * 2 + (l4 - 2));
    *dstp = *(const float4*)ov;
}

// ---------------- pool + classifier (reads split halves + dinv) ----------------
__global__ __launch_bounds__(512) void k_pool_cls(const __half* __restrict__ aggLo,
                                                  const __half* __restrict__ aggHi,
                                                  const float* __restrict__ dinv,
                                                  const float* __restrict__ W2,
                                                  const float* __restrict__ b2,
                                                  const float* __restrict__ g2,
                                                  const float* __restrict__ be2,
                                                  const int* __restrict__ gstart,
                                                  const float* __restrict__ Wc1,
                                                  const float* __restrict__ bc1,
                                                  const float* __restrict__ Wc2,
                                                  const float* __restrict__ bc2,
                                                  float* __restrict__ out) {
    __shared__ float Ws[32 * 64];   // 8 KB
    __shared__ float red[8 * 64];
    int tid = threadIdx.x;
    for (int i = tid; i < 32 * 64; i += 512) Ws[i] = W2[i];
    int g = blockIdx.x;
    int r0 = gstart[g], r1 = gstart[g + 1];
    int wave = tid >> 6, lane = tid & 63;
    float pacc = 0.0f;
    __syncthreads();
    const float4* lo = (const float4*)aggLo;
    const float4* hi = (const float4*)aggHi;
    for (int row = r0 + wave; row < r1; row += 8) {
        float4 r4[4];
        r4[0] = lo[(size_t)row * 2];
        r4[1] = lo[(size_t)row * 2 + 1];
        r4[2] = hi[(size_t)row * 2];
        r4[3] = hi[(size_t)row * 2 + 1];
        float dv = dinv[row];
        const __half2* ah = (const __half2*)r4;
        float dot = 0.f;
#pragma unroll
        for (int k2 = 0; k2 < 16; k2++) {
            float2 f = __half22float2(ah[k2]);
            dot += f.x * Ws[(2 * k2) * 64 + lane] + f.y * Ws[(2 * k2 + 1) * 64 + lane];
        }
        float acc = b2[lane] + dv * dot;
        float s = acc;
#pragma unroll
        for (int m = 32; m >= 1; m >>= 1) s += __shfl_xor(s, m, 64);
        float mu = s * (1.0f / 64.0f);
        float d = acc - mu;
        float v = d * d;
#pragma unroll
        for (int m = 32; m >= 1; m >>= 1) v += __shfl_xor(v, m, 64);
        float val = d * rsqrtf(v * (1.0f / 64.0f) + 1e-5f) * g2[lane] + be2[lane];
        pacc += fmaxf(val, 0.0f);
    }
    red[wave * 64 + lane] = pacc;
    __syncthreads();
    if (wave == 0) {
        float p = 0.f;
#pragma unroll
        for (int w = 0; w < 8; w++) p += red[w * 64 + lane];
        p *= 1.0f / fmaxf((float)(r1 - r0), 1.0f);
        red[lane] = p;
    }
    __syncthreads();
    if (wave == 0 && lane < 32) {
        float zs = bc1[lane];
#pragma unroll
        for (int k = 0; k < 64; k++) zs += red[k] * Wc1[k * 32 + lane];
        float o = fmaxf(zs, 0.0f) * Wc2[lane];
#pragma unroll
        for (int m = 16; m >= 1; m >>= 1) o += __shfl_xor(o, m, 64);
        if (lane == 0) out[g] = o + bc2[0];
    }
}

// ---------------- launch ----------------

extern "C" void kernel_launch(void* const* d_in, const int* in_sizes, int n_in,
                              void* d_out, int out_size, void* d_ws, size_t ws_size,
                              hipStream_t stream) {
    const float* x     = (const float*)d_in[0];
    const int*   ei    = (const int*)d_in[1];
    const int*   batch = (const int*)d_in[2];
    const float* W1  = (const float*)d_in[3];
    const float* b1  = (const float*)d_in[4];
    const float* g1  = (const float*)d_in[5];
    const float* be1 = (const float*)d_in[6];
    const float* W2  = (const float*)d_in[7];
    const float* b2  = (const float*)d_in[8];
    const float* g2  = (const float*)d_in[9];
    const float* be2 = (const float*)d_in[10];
    const float* Wc1 = (const float*)d_in[11];
    const float* bc1 = (const float*)d_in[12];
    const float* Wc2 = (const float*)d_in[13];
    const float* bc2 = (const float*)d_in[14];

    int n = in_sizes[0] / 128;
    int E = in_sizes[1] / 2;
    int G = out_size;                  // 512
    int NB = (n + 255) >> 8;           // 391 coarse buckets

    // ---- workspace layout (~39.6 MB) ----
    float* ws     = (float*)d_ws;
    float* dinv   = ws;                               // n
    int*   deg    = (int*)(dinv + n);                 // n
    int*   offs   = deg + n;                          // n
    int*   gcnt   = offs + n;                         // 512
    int*   gstart = gcnt + 512;                       // 516 (pad, 16B align)
    int*   csr    = gstart + 516;                     // NB*CAP (16 MB)
    __half* h0Lo  = (__half*)(csr + (size_t)NB * CAP);        // n*16 halfs (3.2 MB)
    __half* h0Hi  = h0Lo + (size_t)n * 16;                    // n*16 halfs (3.2 MB)
    int*   bucketed = (int*)(h0Hi + (size_t)n * 16);  // NB*CAP (16 MB)
    __half* h1Lo  = (__half*)bucketed;                // overlays bucketed (dead after bucketB)
    __half* h1Hi  = h1Lo + (size_t)n * 16;

    int nA  = (E + 8191) / 8192;       // 391
    int nG1 = (n + 127) / 128;         // 782
    int nGs = (n + 1024) / 1024;       // 98

    hipMemsetAsync(gcnt, 0, 512 * sizeof(int), stream);

    // K1: bucketA(LDS-sorted) | gemm1(split halves) | gstart
    k_fused1<<<nA + nG1 + nGs, 1024, 0, stream>>>(ei, x, W1, batch, gcnt, bucketed,
                                                  h0Lo, h0Hi, gstart, nA, nG1, NB, n, E, G);
    // K2: fine sort -> csr/offs/deg/dinv, + scale h0 halves by dinv
    k_bucketB<<<NB, 512, 0, stream>>>(bucketed, gcnt, csr, offs, deg, dinv,
                                      h0Lo, h0Hi, n);

    // layer 1: per-half L2-resident gathers (raw sums) -> h1; then LN epilogue -> h0
    k_gather_h<<<(n + 31) / 32, 256, 0, stream>>>(h0Lo, csr, offs, deg, h1Lo, n);
    k_gather_h<<<(n + 31) / 32, 256, 0, stream>>>(h0Hi, csr, offs, deg, h1Hi, n);
    k_ln_split<<<(n + 63) / 64, 256, 0, stream>>>(h1Lo, h1Hi, dinv, b1, g1, be1,
                                                  h0Lo, h0Hi, n);
    // layer 2: per-half gathers (raw sums) -> h1; pool_cls applies dinv
    k_gather_h<<<(n + 31) / 32, 256, 0, stream>>>(h0Lo, csr, offs, deg, h1Lo, n);
    k_gather_h<<<(n + 31) / 32, 256, 0, stream>>>(h0Hi, csr, offs, deg, h1Hi, n);

    k_pool_cls<<<G, 512, 0, stream>>>(h1Lo, h1Hi, dinv, W2, b2, g2, be2, gstart,
                                      Wc1, bc1, Wc2, bc2, (float*)d_out);
}

// Round 15
// 205.433 us; speedup vs baseline: 1.1447x; 1.1447x over previous
//
#include <hip/hip_runtime.h>
#include <hip/hip_fp16.h>

#define CAP 10240      // per-coarse-bucket capacity (mean 8184, +20σ safe)

// ---------------- fused: bucketA(LDS-sorted, coop-copy) | gemm1 | gstart ----------------
__global__ __launch_bounds__(1024) void k_fused1(const int* __restrict__ ei,
                                                 const float* __restrict__ x,
                                                 const float* __restrict__ W1,
                                                 const int* __restrict__ batch,
                                                 int* __restrict__ gcnt,
                                                 int* __restrict__ bucketed,
                                                 __half* __restrict__ hs,
                                                 int* __restrict__ gstart,
                                                 int nA, int nG1, int NB,
                                                 int n, int E, int G) {
    __shared__ __align__(16) char smem[40960];
    int tid = threadIdx.x;
    int bid = blockIdx.x;
    if (bid < nA) {
        // ---- bucketA: register-staged edges -> LDS counting sort -> coop run copy ----
        int* hist = (int*)smem;            // 512 (count -> cursor)
        int* excl = hist + 512;            // 512 (exclusive scan)
        int* gb   = excl + 512;            // 512 (global base per bucket)
        int* ebuf = gb + 512;              // 8192 sorted entries (32 KB)
        const int* src = ei;
        const int* dst = ei + E;
        for (int i = tid; i < 512; i += 1024) hist[i] = 0;
        __syncthreads();
        int e0 = bid * 8192;
        int d[8], sR[8];
#pragma unroll
        for (int k = 0; k < 8; k++) {
            int e = e0 + k * 1024 + tid;
            bool v = e < E;
            d[k]  = v ? dst[e] : -1;
            sR[k] = v ? src[e] : 0;
            if (v) atomicAdd(&hist[d[k] >> 8], 1);
        }
        __syncthreads();
        // exclusive scan of 512 counts (Hillis-Steele)
        if (tid < 512) excl[tid] = hist[tid];
        __syncthreads();
        for (int off = 1; off < 512; off <<= 1) {
            int v2 = 0;
            if (tid < 512) v2 = excl[tid] + ((tid >= off) ? excl[tid - off] : 0);
            __syncthreads();
            if (tid < 512) excl[tid] = v2;
            __syncthreads();
        }
        if (tid < 512) {
            int c = hist[tid];
            int ex = excl[tid] - c;           // exclusive
            excl[tid] = ex;
            gb[tid] = c ? atomicAdd(&gcnt[tid], c) : 0;
            hist[tid] = ex;                   // reuse as LDS cursor
        }
        __syncthreads();
#pragma unroll
        for (int k = 0; k < 8; k++) {
            if (d[k] >= 0) {
                int b = d[k] >> 8;
                int p = atomicAdd(&hist[b], 1);
                ebuf[p] = (sR[k] << 8) | (d[k] & 255);
            }
        }
        __syncthreads();
        // cooperative run copy: 16-lane group per bucket (64B line per step)
        int grp = tid >> 4, l = tid & 15;     // 64 groups
        for (int t = grp; t < 512; t += 64) {
            int lds0 = excl[t];
            int cnt  = hist[t] - lds0;
            int gb0  = gb[t];
            int* dstp = bucketed + (size_t)t * CAP + gb0;
            for (int k = l; k < cnt; k += 16)
                if (gb0 + k < CAP) dstp[k] = ebuf[lds0 + k];
        }
    } else if (bid < nA + nG1) {
        // ---- gemm1: hs = fp16(x @ W1), 128 rows/block, 4 cols/thread ----
        float* Ws = (float*)smem;            // 128*32 fp32 = 16 KB
        const float4* W4 = (const float4*)W1;
        ((float4*)Ws)[tid] = W4[tid];
        __syncthreads();
        int gb2 = bid - nA;
        int row = gb2 * 128 + (tid >> 3);
        int g8 = tid & 7;
        if (row >= n) return;
        const float4* x4 = (const float4*)x;
        const float4* Ws4 = (const float4*)Ws;
        float a0 = 0.f, a1 = 0.f, a2 = 0.f, a3 = 0.f;
#pragma unroll 4
        for (int j = 0; j < 32; j++) {
            float4 xq = x4[(size_t)row * 32 + j];
#pragma unroll
            for (int t = 0; t < 4; t++) {
                float xv = (t == 0) ? xq.x : (t == 1) ? xq.y : (t == 2) ? xq.z : xq.w;
                float4 wv = Ws4[(4 * j + t) * 8 + g8];
                a0 += xv * wv.x; a1 += xv * wv.y; a2 += xv * wv.z; a3 += xv * wv.w;
            }
        }
        __half2 o[2] = { __floats2half2_rn(a0, a1), __floats2half2_rn(a2, a3) };
        *(float2*)(hs + (size_t)row * 32 + g8 * 4) = *(const float2*)o;
    } else {
        // ---- gstart from sorted batch ----
        int i = (bid - nA - nG1) * 1024 + tid;
        if (i > n) return;
        if (i == 0) {
            for (int g = 0; g <= batch[0]; g++) gstart[g] = 0;
        } else if (i == n) {
            for (int g = batch[n - 1] + 1; g <= G; g++) gstart[g] = n;
        } else {
            int b = batch[i], p = batch[i - 1];
            for (int g = p + 1; g <= b; g++) gstart[g] = i;
        }
    }
}

// ---------------- bucketB: fine sort + deg/dinv/offs + hs dinv-scale ----------------
__global__ __launch_bounds__(512) void k_bucketB(const int* __restrict__ bucketed,
                                                 const int* __restrict__ gcnt,
                                                 int* __restrict__ csr,
                                                 int* __restrict__ offs,
                                                 int* __restrict__ deg,
                                                 float* __restrict__ dinv,
                                                 __half* __restrict__ hs, int n) {
    __shared__ int hist[256], scan_a[256], scan_b[256];
    __shared__ float sdinv[256];
    int b = blockIdx.x;
    int tid = threadIdx.x;
    int cnt = min(gcnt[b], CAP);
    int base = b * CAP;                       // fixed-stride csr
    const int* ent = bucketed + (size_t)b * CAP;
    if (tid < 256) hist[tid] = 0;
    __syncthreads();
    for (int i = tid; i < cnt; i += 512) atomicAdd(&hist[ent[i] & 255], 1);
    __syncthreads();
    int h = (tid < 256) ? hist[tid] : 0;
    if (tid < 256) scan_a[tid] = h;
    __syncthreads();
    int* cur = scan_a;
    int* nxt = scan_b;
    for (int off = 1; off < 256; off <<= 1) {
        if (tid < 256) nxt[tid] = cur[tid] + ((tid >= off) ? cur[tid - off] : 0);
        __syncthreads();
        int* tmp = cur; cur = nxt; nxt = tmp;
    }
    if (tid < 256) {
        int ex = cur[tid] - h;
        float dv = rsqrtf((float)(h + 1));    // +1 self-loop
        sdinv[tid] = dv;
        int node = b * 256 + tid;
        if (node < n) {
            offs[node] = base + ex;
            deg[node] = h;
            dinv[node] = dv;
        }
        hist[tid] = ex;      // cursor
    }
    __syncthreads();
    for (int i = tid; i < cnt; i += 512) {
        int v = ent[i];
        int p = atomicAdd(&hist[v & 255], 1);
        csr[base + p] = v >> 8;
    }
    // scale this block's 256 hs rows by dinv
    float4* hsv = (float4*)hs;
#pragma unroll
    for (int p = 0; p < 2; p++) {
        int idx = p * 512 + tid;
        int nl = idx >> 2, cg = idx & 3;
        int node = b * 256 + nl;
        if (node < n) {
            float dv = sdinv[nl];
            float4 raw = hsv[(size_t)node * 4 + cg];
            __half2* h2 = (__half2*)&raw;
            __half2 o[4];
#pragma unroll
            for (int j = 0; j < 4; j++) {
                float2 f = __half22float2(h2[j]);
                o[j] = __floats2half2_rn(f.x * dv, f.y * dv);
            }
            hsv[(size_t)node * 4 + cg] = *(const float4*)o;
        }
    }
}

// ---------------- CSR gather: quarter-wave per row (4 rows/wave) ----------------
template <bool DO_LN>
__global__ __launch_bounds__(256) void k_gather(const __half* __restrict__ hs,
                                                const int* __restrict__ csr,
                                                const int* __restrict__ offs,
                                                const int* __restrict__ deg,
                                                const float* __restrict__ dinv,
                                                const float* __restrict__ b,
                                                const float* __restrict__ g,
                                                const float* __restrict__ be,
                                                __half* __restrict__ out, int n) {
    int wave = threadIdx.x >> 6;
    int lane = threadIdx.x & 63;
    int q   = lane >> 4;      // 0..3 row-quarter
    int l16 = lane & 15;
    int nb  = l16 >> 2;       // 0..3 neighbor slot
    int cg  = l16 & 3;        // 0..3 chan group (16 B)
    int row = blockIdx.x * 16 + wave * 4 + q;
    if (row >= n) return;
    int base = offs[row];
    int dg = deg[row];
    const float4* hsv = (const float4*)hs;
    const float4 fz = make_float4(0.f, 0.f, 0.f, 0.f);
    const __half2 hz = __floats2half2_rn(0.f, 0.f);
    __half2 ha0[4], ha1[4];
#pragma unroll
    for (int j = 0; j < 4; j++) { ha0[j] = hz; ha1[j] = hz; }

    // 2-ahead pipelined loop, dual accumulators (8 neighbors/step per quarter)
    int e = nb;
    float4 r0 = (e     < dg) ? hsv[(size_t)csr[base + e    ] * 4 + cg] : fz;
    float4 r1 = (e + 4 < dg) ? hsv[(size_t)csr[base + e + 4] * 4 + cg] : fz;
    while (e < dg) {
        float4 p0 = (e +  8 < dg) ? hsv[(size_t)csr[base + e +  8] * 4 + cg] : fz;
        float4 p1 = (e + 12 < dg) ? hsv[(size_t)csr[base + e + 12] * 4 + cg] : fz;
        const __half2* h0 = (const __half2*)&r0;
        const __half2* h1 = (const __half2*)&r1;
#pragma unroll
        for (int j = 0; j < 4; j++) {
            ha0[j] = __hadd2(ha0[j], h0[j]);
            ha1[j] = __hadd2(ha1[j], h1[j]);
        }
        r0 = p0; r1 = p1; e += 8;
    }
    // merge in f32, butterfly over the 4 neighbor slots (m = 4, 8)
    float acc[8];
#pragma unroll
    for (int j = 0; j < 4; j++) {
        float2 f0 = __half22float2(ha0[j]);
        float2 f1 = __half22float2(ha1[j]);
        acc[2 * j]     = f0.x + f1.x;
        acc[2 * j + 1] = f0.y + f1.y;
    }
#pragma unroll
    for (int m = 4; m <= 8; m <<= 1)
#pragma unroll
        for (int j = 0; j < 8; j++) acc[j] += __shfl_xor(acc[j], m, 64);
    float dv = dinv[row];
    float4 sraw = hsv[(size_t)row * 4 + cg];
    const __half2* sh2 = (const __half2*)&sraw;
    float a[8];
#pragma unroll
    for (int j = 0; j < 4; j++) {
        float2 f = __half22float2(sh2[j]);
        a[2 * j]     = (acc[2 * j]     + f.x) * dv;
        a[2 * j + 1] = (acc[2 * j + 1] + f.y) * dv;
    }
    if (DO_LN) {
        int c0 = cg * 8;
        float s = 0.f;
#pragma unroll
        for (int j = 0; j < 8; j++) { a[j] += b[c0 + j]; s += a[j]; }
#pragma unroll
        for (int m = 1; m <= 2; m <<= 1) s += __shfl_xor(s, m, 64);
        float mu = s * (1.0f / 32.0f);
        float v2 = 0.f;
#pragma unroll
        for (int j = 0; j < 8; j++) { a[j] -= mu; v2 += a[j] * a[j]; }
#pragma unroll
        for (int m = 1; m <= 2; m <<= 1) v2 += __shfl_xor(v2, m, 64);
        float inv = rsqrtf(v2 * (1.0f / 32.0f) + 1e-5f);
#pragma unroll
        for (int j = 0; j < 8; j++)
            a[j] = fmaxf(a[j] * inv * g[c0 + j] + be[c0 + j], 0.f) * dv;
    }
    if (nb == 0) {
        __half2 o[4];
#pragma unroll
        for (int j = 0; j < 4; j++) o[j] = __floats2half2_rn(a[2 * j], a[2 * j + 1]);
        ((float4*)out)[(size_t)row * 4 + cg] = *(const float4*)o;
    }
}

// ---------------- pool + classifier ----------------
__global__ __launch_bounds__(512) void k_pool_cls(const __half* __restrict__ agg2,
                                                  const float* __restrict__ W2,
                                                  const float* __restrict__ b2,
                                                  const float* __restrict__ g2,
                                                  const float* __restrict__ be2,
                                                  const int* __restrict__ gstart,
                                                  const float* __restrict__ Wc1,
                                                  const float* __restrict__ bc1,
                                                  const float* __restrict__ Wc2,
                                                  const float* __restrict__ bc2,
                                                  float* __restrict__ out) {
    __shared__ float Ws[32 * 64];   // 8 KB
    __shared__ float red[8 * 64];
    int tid = threadIdx.x;
    for (int i = tid; i < 32 * 64; i += 512) Ws[i] = W2[i];
    int g = blockIdx.x;
    int r0 = gstart[g], r1 = gstart[g + 1];
    int wave = tid >> 6, lane = tid & 63;
    float pacc = 0.0f;
    __syncthreads();
    for (int row = r0 + wave; row < r1; row += 8) {
        const float4* a4 = (const float4*)(agg2 + (size_t)row * 32);
        float4 r4[4];
#pragma unroll
        for (int q = 0; q < 4; q++) r4[q] = a4[q];
        const __half2* ah = (const __half2*)r4;
        float acc = b2[lane];
#pragma unroll
        for (int k2 = 0; k2 < 16; k2++) {
            float2 f = __half22float2(ah[k2]);
            acc += f.x * Ws[(2 * k2) * 64 + lane] + f.y * Ws[(2 * k2 + 1) * 64 + lane];
        }
        float s = acc;
#pragma unroll
        for (int m = 32; m >= 1; m >>= 1) s += __shfl_xor(s, m, 64);
        float mu = s * (1.0f / 64.0f);
        float d = acc - mu;
        float v = d * d;
#pragma unroll
        for (int m = 32; m >= 1; m >>= 1) v += __shfl_xor(v, m, 64);
        float val = d * rsqrtf(v * (1.0f / 64.0f) + 1e-5f) * g2[lane] + be2[lane];
        pacc += fmaxf(val, 0.0f);
    }
    red[wave * 64 + lane] = pacc;
    __syncthreads();
    if (wave == 0) {
        float p = 0.f;
#pragma unroll
        for (int w = 0; w < 8; w++) p += red[w * 64 + lane];
        p *= 1.0f / fmaxf((float)(r1 - r0), 1.0f);
        red[lane] = p;
    }
    __syncthreads();
    if (wave == 0 && lane < 32) {
        float zs = bc1[lane];
#pragma unroll
        for (int k = 0; k < 64; k++) zs += red[k] * Wc1[k * 32 + lane];
        float o = fmaxf(zs, 0.0f) * Wc2[lane];
#pragma unroll
        for (int m = 16; m >= 1; m >>= 1) o += __shfl_xor(o, m, 64);
        if (lane == 0) out[g] = o + bc2[0];
    }
}

// ---------------- launch ----------------

extern "C" void kernel_launch(void* const* d_in, const int* in_sizes, int n_in,
                              void* d_out, int out_size, void* d_ws, size_t ws_size,
                              hipStream_t stream) {
    const float* x     = (const float*)d_in[0];
    const int*   ei    = (const int*)d_in[1];
    const int*   batch = (const int*)d_in[2];
    const float* W1  = (const float*)d_in[3];
    const float* b1  = (const float*)d_in[4];
    const float* g1  = (const float*)d_in[5];
    const float* be1 = (const float*)d_in[6];
    const float* W2  = (const float*)d_in[7];
    const float* b2  = (const float*)d_in[8];
    const float* g2  = (const float*)d_in[9];
    const float* be2 = (const float*)d_in[10];
    const float* Wc1 = (const float*)d_in[11];
    const float* bc1 = (const float*)d_in[12];
    const float* Wc2 = (const float*)d_in[13];
    const float* bc2 = (const float*)d_in[14];

    int n = in_sizes[0] / 128;
    int E = in_sizes[1] / 2;
    int G = out_size;                  // 512
    int NB = (n + 255) >> 8;           // 391 coarse buckets

    // ---- workspace layout (~39.6 MB) ----
    float* ws     = (float*)d_ws;
    float* dinv   = ws;                               // n
    int*   deg    = (int*)(dinv + n);                 // n
    int*   offs   = deg + n;                          // n
    int*   gcnt   = offs + n;                         // 512
    int*   gstart = gcnt + 512;                       // 516 (pad, 16B align)
    int*   csr    = gstart + 516;                     // NB*CAP (16 MB)
    __half* hsA   = (__half*)(csr + (size_t)NB * CAP);        // n*32 halfs (6.4 MB)
    int*   bucketed = (int*)(hsA + (size_t)n * 32);   // NB*CAP (16 MB)
    __half* hsB   = (__half*)bucketed;                // overlays bucketed

    int nA  = (E + 8191) / 8192;       // 391
    int nG1 = (n + 127) / 128;         // 782
    int nGs = (n + 1024) / 1024;       // 98

    hipMemsetAsync(gcnt, 0, 512 * sizeof(int), stream);

    // K1: bucketA(LDS-sorted, coop copy) | gemm1 | gstart
    k_fused1<<<nA + nG1 + nGs, 1024, 0, stream>>>(ei, x, W1, batch, gcnt, bucketed,
                                                  hsA, gstart, nA, nG1, NB, n, E, G);
    // K2: fine sort -> csr/offs/deg/dinv, + scale hsA rows by dinv
    k_bucketB<<<NB, 512, 0, stream>>>(bucketed, gcnt, csr, offs, deg, dinv, hsA, n);

    // K3: layer-1 aggregate + fused bias/LN/ReLU/dinv -> hsB
    k_gather<true><<<(n + 15) / 16, 256, 0, stream>>>(hsA, csr, offs, deg, dinv,
                                                      b1, g1, be1, hsB, n);
    // K4: layer-2 aggregate -> agg2 (into hsA region)
    k_gather<false><<<(n + 15) / 16, 256, 0, stream>>>(hsB, csr, offs, deg, dinv,
                                                       nullptr, nullptr, nullptr, hsA, n);
    // K5: GEMV+LN+ReLU+mean-pool+classifier
    k_pool_cls<<<G, 512, 0, stream>>>(hsA, W2, b2, g2, be2, gstart,
                                      Wc1, bc1, Wc2, bc2, (float*)d_out);
}